// Round 11
// baseline (249.508 us; speedup 1.0000x reference)
//
#include <hip/hip_runtime.h>
#include <hip/hip_bf16.h>

// TripletBatchHardLoss: N=8192, D=256, fp32 embeddings (L2-normalized), int32 labels.
// Normalized -> pdist monotone DECREASING in dot:
//   hard_negative = max dot over negs, hard_positive = min dot over poss (diag dot~1 safe).
// R11 = R8 skeleton (2080 upper-triangle 128x128 blocks, A+B via global_load_lds,
// triple-buffered LDS, launch_bounds(256,3) -> 84 VGPR no-spill) with:
//  - ONE barrier per K-iter (8 vs R8's 15): vmcnt(4); s_barrier; issue DMA(kt+2);
//    ds_read buf[kt%3]; MFMA. Data-ready: barrier follows each wave's drain of tile kt.
//    WAR: DMA(kt+2) clobbers buf[(kt+2)%3] whose last readers (body kt-1) retired
//    before this barrier (MFMA issue forces lgkm retirement).
//  - true depth-2 prefetch: DMA issued AFTER the wait -> vmcnt(4) drains exactly tile kt
//    (R8 issued before the wait, accidentally draining kt+1 too).
//  - finalize merged into tile_kernel: threadfence + done-counter, last block computes
//    the mean (one fewer launch).
// VGPR discipline (R7/R10 lessons): (256,3)=84 clean; (256,4)=64 spills; (256,5)=48 disaster.

#define NS 8192
#define DD 256
#define EPS_PD 1e-12f
#define BIGF 1e30f

typedef unsigned short u16;
typedef unsigned int u32;
typedef short short8 __attribute__((ext_vector_type(8)));
typedef float f32x4 __attribute__((ext_vector_type(4)));

typedef const __attribute__((address_space(1))) u32 glb_u32;
typedef __attribute__((address_space(3))) u32 lds_u32;

__device__ __forceinline__ void async16(const void* g, void* l) {
    __builtin_amdgcn_global_load_lds((glb_u32*)g, (lds_u32*)l, 16, 0, 0);
}

// order-preserving float <-> uint key (unsigned compare == float compare)
__device__ __forceinline__ u32 fkey(float f) {
    u32 b = __float_as_uint(f);
    return (b & 0x80000000u) ? ~b : (b | 0x80000000u);
}
__device__ __forceinline__ float unkey(u32 k) {
    u32 b = (k & 0x80000000u) ? (k ^ 0x80000000u) : ~k;
    return __uint_as_float(b);
}

__device__ __forceinline__ u16 f2bf_rne(float f) {
    u32 b = __float_as_uint(f);
    b += 0x7FFFu + ((b >> 16) & 1u);
    return (u16)(b >> 16);
}

// DPP lane-move within 16-lane rows (reduction groups are exactly DPP rows)
template <int CTRL>
__device__ __forceinline__ float dpp_mov(float x) {
    return __int_as_float(
        __builtin_amdgcn_update_dpp(0, __float_as_int(x), CTRL, 0xF, 0xF, true));
}

// ---------------- kernel 1: fp32 -> bf16, row sum-of-squares, init keys ----------------
__global__ __launch_bounds__(256) void prep_kernel(
    const float* __restrict__ e, u16* __restrict__ ebf, float* __restrict__ sq,
    u32* __restrict__ mxk, u32* __restrict__ mnk, u32* __restrict__ done,
    float* __restrict__ out) {
    const int tid = blockIdx.x * 256 + threadIdx.x;   // 2048 blocks
    const int row = tid >> 6, t = tid & 63;           // one wave per row
    float4 v = ((const float4*)(e + (size_t)row * DD))[t];
    ushort4 u;
    u.x = f2bf_rne(v.x); u.y = f2bf_rne(v.y); u.z = f2bf_rne(v.z); u.w = f2bf_rne(v.w);
    ((ushort4*)(ebf + (size_t)row * DD))[t] = u;
    float s = v.x * v.x + v.y * v.y + v.z * v.z + v.w * v.w;
    for (int o = 32; o; o >>= 1) s += __shfl_down(s, o);
    if (t == 0) {
        sq[row] = s;
        mxk[row] = 0u;            // sentinel for unsigned max
        mnk[row] = 0xFFFFFFFFu;   // sentinel for unsigned min
        if (row == 0) { *done = 0u; out[0] = 0.0f; }
    }
}

// ------- kernel 2: triple-buffered triangular dot-GEMM + reduction + fused finalize -------
__global__ __launch_bounds__(256, 3) void tile_kernel(
    const u16* __restrict__ ebf, const int* __restrict__ labels,
    u32* __restrict__ mxk, u32* __restrict__ mnk,
    const float* __restrict__ sq, u32* __restrict__ done, float* __restrict__ out) {
    // 3 x (128x32) tiles each; 16B chunk (row,c) at slot row*4 + (c^((row>>2)&3))
    __shared__ __attribute__((aligned(16))) u16 lds_a[3][128 * 32];   // 3 x 8 KB
    __shared__ __attribute__((aligned(16))) u16 lds_b[3][128 * 32];   // 3 x 8 KB

    // decode linear triangle index -> (i <= j)
    const int t = blockIdx.x;
    int j = (int)((sqrtf(8.0f * (float)t + 1.0f) - 1.0f) * 0.5f);
    while ((j + 1) * (j + 2) / 2 <= t) ++j;
    while (j * (j + 1) / 2 > t) --j;
    const int i = t - j * (j + 1) / 2;
    const int bi = i * 128, bj = j * 128;

    const int tid = threadIdx.x;
    const int lane = tid & 63, wid = tid >> 6;
    const int wm = wid >> 1, wn = wid & 1;
    const int l15 = lane & 15, q = lane >> 4;

    // staging: wave wid owns slots [wid*128, wid*128+128) of each 512-slot tile
    const int s0 = wid * 128 + lane, s1 = s0 + 64;
    const int r0 = s0 >> 2, c0 = (s0 & 3) ^ ((r0 >> 2) & 3);
    const int r1 = s1 >> 2, c1 = (s1 & 3) ^ ((r1 >> 2) & 3);
    const u16* gA0 = ebf + (size_t)(bi + r0) * DD + c0 * 8;
    const u16* gA1 = ebf + (size_t)(bi + r1) * DD + c1 * 8;
    const u16* gB0 = ebf + (size_t)(bj + r0) * DD + c0 * 8;
    const u16* gB1 = ebf + (size_t)(bj + r1) * DD + c1 * 8;
    const int ldst0 = wid * 128 * 8, ldst1 = ldst0 + 64 * 8;

    // frag-read offsets (u16 elems): row = base+l15, chunk q -> slot row*4 + (q^((row>>2)&3))
    const int swz = (q ^ (l15 >> 2)) * 8;
    const int offa = (wm * 64 + l15) * 32 + swz;
    const int offb = (wn * 64 + l15) * 32 + swz;

    // prologue: DMA tiles 0 and 1 (4 instrs each; 8 outstanding)
    async16(gA0, &lds_a[0][ldst0]); async16(gA1, &lds_a[0][ldst1]);
    async16(gB0, &lds_b[0][ldst0]); async16(gB1, &lds_b[0][ldst1]);
    async16(gA0 + 32, &lds_a[1][ldst0]); async16(gA1 + 32, &lds_a[1][ldst1]);
    async16(gB0 + 32, &lds_b[1][ldst0]); async16(gB1 + 32, &lds_b[1][ldst1]);

    f32x4 acc[4][4] = {};
#pragma unroll
    for (int kt = 0; kt < 8; ++kt) {
        const int cur = kt % 3;
        // drain exactly tile kt's 4 DMAs (issued two bodies ago); tile kt+1 stays in flight
        if (kt < 7) asm volatile("s_waitcnt vmcnt(4)\n\ts_barrier" ::: "memory");
        else        asm volatile("s_waitcnt vmcnt(0)\n\ts_barrier" ::: "memory");
        if (kt < 6) {   // refill the buffer last read in body kt-1 (all readers retired)
            const int nb = (kt + 2) % 3;
            const int ko = (kt + 2) * 32;
            async16(gA0 + ko, &lds_a[nb][ldst0]); async16(gA1 + ko, &lds_a[nb][ldst1]);
            async16(gB0 + ko, &lds_b[nb][ldst0]); async16(gB1 + ko, &lds_b[nb][ldst1]);
        }
        short8 af[4], bfr[4];
#pragma unroll
        for (int mi = 0; mi < 4; ++mi)
            af[mi] = *(const short8*)(&lds_a[cur][offa + mi * 512]);
#pragma unroll
        for (int ni = 0; ni < 4; ++ni)
            bfr[ni] = *(const short8*)(&lds_b[cur][offb + ni * 512]);
#pragma unroll
        for (int mi = 0; mi < 4; ++mi)
#pragma unroll
            for (int ni = 0; ni < 4; ++ni)
                acc[mi][ni] = __builtin_amdgcn_mfma_f32_16x16x32_bf16(
                    af[mi], bfr[ni], acc[mi][ni], 0, 0, 0);
    }

    // ---- epilogue: C/D layout col = lane&15, row = q*4 + reg (m89-verified) ----
    int li[4][4];
#pragma unroll
    for (int mi = 0; mi < 4; ++mi) {
        const int4 v = *(const int4*)(labels + bi + wm * 64 + mi * 16 + q * 4);
        li[mi][0] = v.x; li[mi][1] = v.y; li[mi][2] = v.z; li[mi][3] = v.w;
    }
    int lj[4];
#pragma unroll
    for (int ni = 0; ni < 4; ++ni) lj[ni] = labels[bj + wn * 64 + ni * 16 + l15];

    float mxn[4][4], mnp[4][4];                        // row-side per (mi, r)
    float mxc[4] = {-BIGF, -BIGF, -BIGF, -BIGF};       // col-side per ni
    float mnc[4] = {BIGF, BIGF, BIGF, BIGF};
#pragma unroll
    for (int mi = 0; mi < 4; ++mi)
#pragma unroll
        for (int r = 0; r < 4; ++r) { mxn[mi][r] = -BIGF; mnp[mi][r] = BIGF; }

#pragma unroll
    for (int mi = 0; mi < 4; ++mi)
#pragma unroll
        for (int ni = 0; ni < 4; ++ni) {
            const int l = lj[ni];
#pragma unroll
            for (int r = 0; r < 4; ++r) {
                const float d = acc[mi][ni][r];
                const bool same = (li[mi][r] == l);
                const float sneg = same ? -BIGF : d;
                const float spos = same ? d : BIGF;
                mxn[mi][r] = fmaxf(mxn[mi][r], sneg);
                mnp[mi][r] = fminf(mnp[mi][r], spos);
                mxc[ni] = fmaxf(mxc[ni], sneg);
                mnc[ni] = fminf(mnc[ni], spos);
            }
        }

    // col-side: reduce over q (lanes l15, +16, +32, +48) via shfl_xor 16/32
#pragma unroll
    for (int ni = 0; ni < 4; ++ni) {
        mxc[ni] = fmaxf(mxc[ni], __shfl_xor(mxc[ni], 16));
        mnc[ni] = fminf(mnc[ni], __shfl_xor(mnc[ni], 16));
        mxc[ni] = fmaxf(mxc[ni], __shfl_xor(mxc[ni], 32));
        mnc[ni] = fminf(mnc[ni], __shfl_xor(mnc[ni], 32));
    }
    if (q == 0) {
#pragma unroll
        for (int ni = 0; ni < 4; ++ni) {
            const int col = bj + wn * 64 + ni * 16 + l15;
            atomicMax(&mxk[col], fkey(mxc[ni]));
            atomicMin(&mnk[col], fkey(mnc[ni]));
        }
    }
    // row-side: 16-lane DPP reduction (xor1, xor2, ror4, ror8) + atomics
#pragma unroll
    for (int mi = 0; mi < 4; ++mi)
#pragma unroll
        for (int r = 0; r < 4; ++r) {
            float x = mxn[mi][r], n = mnp[mi][r];
            x = fmaxf(x, dpp_mov<0xB1>(x));  n = fminf(n, dpp_mov<0xB1>(n));
            x = fmaxf(x, dpp_mov<0x4E>(x));  n = fminf(n, dpp_mov<0x4E>(n));
            x = fmaxf(x, dpp_mov<0x124>(x)); n = fminf(n, dpp_mov<0x124>(n));
            x = fmaxf(x, dpp_mov<0x128>(x)); n = fminf(n, dpp_mov<0x128>(n));
            if (l15 == 0) {
                const int row = bi + wm * 64 + mi * 16 + q * 4 + r;
                atomicMax(&mxk[row], fkey(x));
                atomicMin(&mnk[row], fkey(n));
            }
        }

    // ---- fused finalize: last block computes the mean ----
    __threadfence();   // make this block's atomics visible before signaling
    __shared__ int lastFlag;
    if (tid == 0) lastFlag = (atomicAdd(done, 1u) == 2079u);
    __syncthreads();
    if (!lastFlag) return;
    __threadfence();   // acquire: observe all blocks' atomics
    float part = 0.0f;
    for (int r = tid; r < NS; r += 256) {
        const float s = sq[r] + 1.0f;   // sq_i + sq_j, sq_j = 1 +- 1e-7
        const float hn = sqrtf(fmaxf(fmaf(-2.0f, unkey(mxk[r]), s), EPS_PD));
        const float hp = sqrtf(fmaxf(fmaf(-2.0f, unkey(mnk[r]), s), EPS_PD));
        part += fmaxf(hp - hn + 1.0f, 0.0f);
    }
    for (int o = 32; o; o >>= 1) part += __shfl_down(part, o);
    __shared__ float wsum[4];
    if (lane == 0) wsum[wid] = part;
    __syncthreads();
    if (tid == 0) out[0] = (wsum[0] + wsum[1] + wsum[2] + wsum[3]) * (1.0f / NS);
}

extern "C" void kernel_launch(void* const* d_in, const int* in_sizes, int n_in,
                              void* d_out, int out_size, void* d_ws, size_t ws_size,
                              hipStream_t stream) {
    const int* labels = (const int*)d_in[0];
    const float* emb = (const float*)d_in[1];
    float* out = (float*)d_out;

    char* ws = (char*)d_ws;
    u16* ebf = (u16*)ws;                                     // 4 MB
    float* sq = (float*)(ws + (size_t)NS * DD * 2);          // 32 KB
    u32* mxk = (u32*)(ws + (size_t)NS * DD * 2 + NS * 4);
    u32* mnk = mxk + NS;
    u32* done = mnk + NS;

    prep_kernel<<<NS * DD / 4 / 256, 256, 0, stream>>>(emb, ebf, sq, mxk, mnk, done, out);
    tile_kernel<<<2080, 256, 0, stream>>>(ebf, labels, mxk, mnk, sq, done, out);
}

// Round 12
// 109.568 us; speedup vs baseline: 2.2772x; 2.2772x over previous
//
#include <hip/hip_runtime.h>
#include <hip/hip_bf16.h>

// TripletBatchHardLoss: N=8192, D=256, fp32 embeddings (L2-normalized), int32 labels.
// Normalized -> pdist monotone DECREASING in dot:
//   hard_negative = max dot over negs, hard_positive = min dot over poss (diag dot~1 safe).
// R12 = R11's one-barrier K-loop WITHOUT the fused finalize (R11 post-mortem: the
// per-block __threadfence = per-XCD L2 writeback x 2080 blocks ~ +130 us; removed).
// Structure: 2080 upper-triangle 128x128 blocks, A+B via global_load_lds, triple-buffered
// LDS, ONE barrier per K-iter:
//   vmcnt(4) [drains exactly tile kt, issued two bodies earlier]; s_barrier;
//   issue DMA(kt+2) into buf[(kt+2)%3]; ds_read buf[kt%3]; MFMA.
// WAR-safe: DMA(kt+2) clobbers the buffer read in body kt-1; every wave passed this
// barrier only after body kt-1's ds_reads retired (lgkm forced before MFMA issue).
// VGPR discipline: (256,3)=84 clean; (256,4)=64 spills; (256,5)=48 disaster.
// Separate finalize kernel (cross-launch ordering is free; threadfence is not).

#define NS 8192
#define DD 256
#define EPS_PD 1e-12f
#define BIGF 1e30f

typedef unsigned short u16;
typedef unsigned int u32;
typedef short short8 __attribute__((ext_vector_type(8)));
typedef float f32x4 __attribute__((ext_vector_type(4)));

typedef const __attribute__((address_space(1))) u32 glb_u32;
typedef __attribute__((address_space(3))) u32 lds_u32;

__device__ __forceinline__ void async16(const void* g, void* l) {
    __builtin_amdgcn_global_load_lds((glb_u32*)g, (lds_u32*)l, 16, 0, 0);
}

// order-preserving float <-> uint key (unsigned compare == float compare)
__device__ __forceinline__ u32 fkey(float f) {
    u32 b = __float_as_uint(f);
    return (b & 0x80000000u) ? ~b : (b | 0x80000000u);
}
__device__ __forceinline__ float unkey(u32 k) {
    u32 b = (k & 0x80000000u) ? (k ^ 0x80000000u) : ~k;
    return __uint_as_float(b);
}

__device__ __forceinline__ u16 f2bf_rne(float f) {
    u32 b = __float_as_uint(f);
    b += 0x7FFFu + ((b >> 16) & 1u);
    return (u16)(b >> 16);
}

// DPP lane-move within 16-lane rows (reduction groups are exactly DPP rows)
template <int CTRL>
__device__ __forceinline__ float dpp_mov(float x) {
    return __int_as_float(
        __builtin_amdgcn_update_dpp(0, __float_as_int(x), CTRL, 0xF, 0xF, true));
}

// ---------------- kernel 1: fp32 -> bf16, row sum-of-squares, init keys ----------------
__global__ __launch_bounds__(256) void prep_kernel(
    const float* __restrict__ e, u16* __restrict__ ebf, float* __restrict__ sq,
    u32* __restrict__ mxk, u32* __restrict__ mnk, float* __restrict__ out) {
    const int tid = blockIdx.x * 256 + threadIdx.x;   // 2048 blocks
    const int row = tid >> 6, t = tid & 63;           // one wave per row
    float4 v = ((const float4*)(e + (size_t)row * DD))[t];
    ushort4 u;
    u.x = f2bf_rne(v.x); u.y = f2bf_rne(v.y); u.z = f2bf_rne(v.z); u.w = f2bf_rne(v.w);
    ((ushort4*)(ebf + (size_t)row * DD))[t] = u;
    float s = v.x * v.x + v.y * v.y + v.z * v.z + v.w * v.w;
    for (int o = 32; o; o >>= 1) s += __shfl_down(s, o);
    if (t == 0) {
        sq[row] = s;
        mxk[row] = 0u;            // sentinel for unsigned max
        mnk[row] = 0xFFFFFFFFu;   // sentinel for unsigned min
        if (row == 0) out[0] = 0.0f;
    }
}

// ---------------- kernel 2: triple-buffered triangular dot-GEMM + two-sided reduction -----
__global__ __launch_bounds__(256, 3) void tile_kernel(
    const u16* __restrict__ ebf, const int* __restrict__ labels,
    u32* __restrict__ mxk, u32* __restrict__ mnk) {
    // 3 x (128x32) tiles each; 16B chunk (row,c) at slot row*4 + (c^((row>>2)&3))
    __shared__ __attribute__((aligned(16))) u16 lds_a[3][128 * 32];   // 3 x 8 KB
    __shared__ __attribute__((aligned(16))) u16 lds_b[3][128 * 32];   // 3 x 8 KB

    // decode linear triangle index -> (i <= j)
    const int t = blockIdx.x;
    int j = (int)((sqrtf(8.0f * (float)t + 1.0f) - 1.0f) * 0.5f);
    while ((j + 1) * (j + 2) / 2 <= t) ++j;
    while (j * (j + 1) / 2 > t) --j;
    const int i = t - j * (j + 1) / 2;
    const int bi = i * 128, bj = j * 128;

    const int tid = threadIdx.x;
    const int lane = tid & 63, wid = tid >> 6;
    const int wm = wid >> 1, wn = wid & 1;
    const int l15 = lane & 15, q = lane >> 4;

    // staging: wave wid owns slots [wid*128, wid*128+128) of each 512-slot tile
    const int s0 = wid * 128 + lane, s1 = s0 + 64;
    const int r0 = s0 >> 2, c0 = (s0 & 3) ^ ((r0 >> 2) & 3);
    const int r1 = s1 >> 2, c1 = (s1 & 3) ^ ((r1 >> 2) & 3);
    const u16* gA0 = ebf + (size_t)(bi + r0) * DD + c0 * 8;
    const u16* gA1 = ebf + (size_t)(bi + r1) * DD + c1 * 8;
    const u16* gB0 = ebf + (size_t)(bj + r0) * DD + c0 * 8;
    const u16* gB1 = ebf + (size_t)(bj + r1) * DD + c1 * 8;
    const int ldst0 = wid * 128 * 8, ldst1 = ldst0 + 64 * 8;

    // frag-read offsets (u16 elems): row = base+l15, chunk q -> slot row*4 + (q^((row>>2)&3))
    const int swz = (q ^ (l15 >> 2)) * 8;
    const int offa = (wm * 64 + l15) * 32 + swz;
    const int offb = (wn * 64 + l15) * 32 + swz;

    // prologue: DMA tiles 0 and 1 (4 instrs each; 8 outstanding)
    async16(gA0, &lds_a[0][ldst0]); async16(gA1, &lds_a[0][ldst1]);
    async16(gB0, &lds_b[0][ldst0]); async16(gB1, &lds_b[0][ldst1]);
    async16(gA0 + 32, &lds_a[1][ldst0]); async16(gA1 + 32, &lds_a[1][ldst1]);
    async16(gB0 + 32, &lds_b[1][ldst0]); async16(gB1 + 32, &lds_b[1][ldst1]);

    f32x4 acc[4][4] = {};
#pragma unroll
    for (int kt = 0; kt < 8; ++kt) {
        const int cur = kt % 3;
        // drain exactly tile kt's 4 DMAs (issued two bodies ago); tile kt+1 stays in flight
        if (kt < 7) asm volatile("s_waitcnt vmcnt(4)\n\ts_barrier" ::: "memory");
        else        asm volatile("s_waitcnt vmcnt(0)\n\ts_barrier" ::: "memory");
        if (kt < 6) {   // refill the buffer last read in body kt-1 (all readers retired)
            const int nb = (kt + 2) % 3;
            const int ko = (kt + 2) * 32;
            async16(gA0 + ko, &lds_a[nb][ldst0]); async16(gA1 + ko, &lds_a[nb][ldst1]);
            async16(gB0 + ko, &lds_b[nb][ldst0]); async16(gB1 + ko, &lds_b[nb][ldst1]);
        }
        short8 af[4], bfr[4];
#pragma unroll
        for (int mi = 0; mi < 4; ++mi)
            af[mi] = *(const short8*)(&lds_a[cur][offa + mi * 512]);
#pragma unroll
        for (int ni = 0; ni < 4; ++ni)
            bfr[ni] = *(const short8*)(&lds_b[cur][offb + ni * 512]);
#pragma unroll
        for (int mi = 0; mi < 4; ++mi)
#pragma unroll
            for (int ni = 0; ni < 4; ++ni)
                acc[mi][ni] = __builtin_amdgcn_mfma_f32_16x16x32_bf16(
                    af[mi], bfr[ni], acc[mi][ni], 0, 0, 0);
    }

    // ---- epilogue: C/D layout col = lane&15, row = q*4 + reg (m89-verified) ----
    int li[4][4];
#pragma unroll
    for (int mi = 0; mi < 4; ++mi) {
        const int4 v = *(const int4*)(labels + bi + wm * 64 + mi * 16 + q * 4);
        li[mi][0] = v.x; li[mi][1] = v.y; li[mi][2] = v.z; li[mi][3] = v.w;
    }
    int lj[4];
#pragma unroll
    for (int ni = 0; ni < 4; ++ni) lj[ni] = labels[bj + wn * 64 + ni * 16 + l15];

    float mxn[4][4], mnp[4][4];                        // row-side per (mi, r)
    float mxc[4] = {-BIGF, -BIGF, -BIGF, -BIGF};       // col-side per ni
    float mnc[4] = {BIGF, BIGF, BIGF, BIGF};
#pragma unroll
    for (int mi = 0; mi < 4; ++mi)
#pragma unroll
        for (int r = 0; r < 4; ++r) { mxn[mi][r] = -BIGF; mnp[mi][r] = BIGF; }

#pragma unroll
    for (int mi = 0; mi < 4; ++mi)
#pragma unroll
        for (int ni = 0; ni < 4; ++ni) {
            const int l = lj[ni];
#pragma unroll
            for (int r = 0; r < 4; ++r) {
                const float d = acc[mi][ni][r];
                const bool same = (li[mi][r] == l);
                const float sneg = same ? -BIGF : d;
                const float spos = same ? d : BIGF;
                mxn[mi][r] = fmaxf(mxn[mi][r], sneg);
                mnp[mi][r] = fminf(mnp[mi][r], spos);
                mxc[ni] = fmaxf(mxc[ni], sneg);
                mnc[ni] = fminf(mnc[ni], spos);
            }
        }

    // col-side: reduce over q (lanes l15, +16, +32, +48) via shfl_xor 16/32
#pragma unroll
    for (int ni = 0; ni < 4; ++ni) {
        mxc[ni] = fmaxf(mxc[ni], __shfl_xor(mxc[ni], 16));
        mnc[ni] = fminf(mnc[ni], __shfl_xor(mnc[ni], 16));
        mxc[ni] = fmaxf(mxc[ni], __shfl_xor(mxc[ni], 32));
        mnc[ni] = fminf(mnc[ni], __shfl_xor(mnc[ni], 32));
    }
    if (q == 0) {
#pragma unroll
        for (int ni = 0; ni < 4; ++ni) {
            const int col = bj + wn * 64 + ni * 16 + l15;
            atomicMax(&mxk[col], fkey(mxc[ni]));
            atomicMin(&mnk[col], fkey(mnc[ni]));
        }
    }
    // row-side: 16-lane DPP reduction (xor1, xor2, ror4, ror8) + atomics
#pragma unroll
    for (int mi = 0; mi < 4; ++mi)
#pragma unroll
        for (int r = 0; r < 4; ++r) {
            float x = mxn[mi][r], n = mnp[mi][r];
            x = fmaxf(x, dpp_mov<0xB1>(x));  n = fminf(n, dpp_mov<0xB1>(n));
            x = fmaxf(x, dpp_mov<0x4E>(x));  n = fminf(n, dpp_mov<0x4E>(n));
            x = fmaxf(x, dpp_mov<0x124>(x)); n = fminf(n, dpp_mov<0x124>(n));
            x = fmaxf(x, dpp_mov<0x128>(x)); n = fminf(n, dpp_mov<0x128>(n));
            if (l15 == 0) {
                const int row = bi + wm * 64 + mi * 16 + q * 4 + r;
                atomicMax(&mxk[row], fkey(x));
                atomicMin(&mnk[row], fkey(n));
            }
        }
}

// ---------------- kernel 3: per-row loss + mean ----------------
__global__ __launch_bounds__(256) void finalize_kernel(
    const u32* __restrict__ mxk, const u32* __restrict__ mnk,
    const float* __restrict__ sq, float* __restrict__ out) {
    const int i = blockIdx.x * 256 + threadIdx.x;
    const float s = sq[i] + 1.0f;   // sq_i + sq_j, sq_j = 1 +- 1e-7
    const float hn = sqrtf(fmaxf(fmaf(-2.0f, unkey(mxk[i]), s), EPS_PD));
    const float hp = sqrtf(fmaxf(fmaf(-2.0f, unkey(mnk[i]), s), EPS_PD));
    float loss = fmaxf(hp - hn + 1.0f, 0.0f);
    for (int o = 32; o; o >>= 1) loss += __shfl_down(loss, o);
    __shared__ float wsum[4];
    const int lane = threadIdx.x & 63, w = threadIdx.x >> 6;
    if (lane == 0) wsum[w] = loss;
    __syncthreads();
    if (threadIdx.x == 0)
        atomicAdd(out, (wsum[0] + wsum[1] + wsum[2] + wsum[3]) * (1.0f / NS));
}

extern "C" void kernel_launch(void* const* d_in, const int* in_sizes, int n_in,
                              void* d_out, int out_size, void* d_ws, size_t ws_size,
                              hipStream_t stream) {
    const int* labels = (const int*)d_in[0];
    const float* emb = (const float*)d_in[1];
    float* out = (float*)d_out;

    char* ws = (char*)d_ws;
    u16* ebf = (u16*)ws;                                     // 4 MB
    float* sq = (float*)(ws + (size_t)NS * DD * 2);          // 32 KB
    u32* mxk = (u32*)(ws + (size_t)NS * DD * 2 + NS * 4);
    u32* mnk = mxk + NS;

    prep_kernel<<<NS * DD / 4 / 256, 256, 0, stream>>>(emb, ebf, sq, mxk, mnk, out);
    tile_kernel<<<2080, 256, 0, stream>>>(ebf, labels, mxk, mnk);
    finalize_kernel<<<NS / 256, 256, 0, stream>>>(mxk, mnk, sq, out);
}